// Round 13
// baseline (125.728 us; speedup 1.0000x reference)
//
#include <hip/hip_runtime.h>
#include <math.h>

#define NUM_HEADS 16
#define DIM_HID 64
#define NUM_GAUSS 251
#define W_SCA_COLS 320   // DIM_HID + 256
#define GP 20            // padded stride (floats): 80B, 16B-aligned
#define RAD 0.14f        // window radius
#define NW 8             // fixed window iterations
#define TPB 256
#define EPB 256

typedef float f4 __attribute__((ext_vector_type(4)));
struct F3 { float x, y, z; };

// ---------------------------------------------------------------------------
// r13: ABLATION ROUND (one-time). Six rounds of falsified single-cause
// theories (LDS count r5, occupancy r8, store scatter r9, prologue r12;
// derived PMC counters proven broken in r7) -> measure, don't guess.
// Five dispatches, r11 skeleton (22.0us best):
//   MODE 1 FULLx3      inflated reference
//   MODE 2 NOSTOREx3   global stores -> asm sinks (rule #17: keep live)
//   MODE 3 NOGATHERx3  pos gather -> computed pos, idx sunk
//   MODE 4 SKELx3      loads+stores only (no gauss, no gate)
//   MODE 0 FULLx1      exact r11, LAST -> correct final output
// Reported dur_us = sum (sacrificial). rocprof rows give per-mode dur.
// ---------------------------------------------------------------------------
template<int MODE, int REPS>
__global__ __launch_bounds__(TPB, 4) void edge_kernel(
    const int* __restrict__ idxA,
    const int* __restrict__ idxB,
    const float* __restrict__ feat,
    const float* __restrict__ pos,
    const float* __restrict__ w_edge,
    const float* __restrict__ w_vec1,
    const float* __restrict__ w_vec2,
    const float* __restrict__ w_sca,
    const float* __restrict__ w_gate,
    const float* __restrict__ b_gate,
    float* __restrict__ out,
    int E)
{
    __shared__ __align__(16) float wg[NUM_GAUSS * GP];
    __shared__ __align__(16) float wt5[5 * GP];
    __shared__ __align__(16) float weff[64];
    __shared__ __align__(16) float As[16], Bs[16];
    __shared__ __align__(16) float sOut[4][64 * GP];

    const int tid = threadIdx.x;
    const int e  = blockIdx.x * EPB + tid;
    const bool act = (e < E);
    const int ec = act ? e : (E - 1);

    // --- block prologue (common to all modes) ---
    for (int j = tid; j < 16 * NUM_GAUSS; j += TPB) {
        int o = j / NUM_GAUSS;
        int g = j - o * NUM_GAUSS;
        wg[g * GP + o] = w_sca[o * W_SCA_COLS + DIM_HID + g];
    }
    if (tid < 80) {
        int t = tid >> 4, o = tid & 15;
        wt5[t * GP + o] = w_sca[o * W_SCA_COLS + DIM_HID + NUM_GAUSS + t];
    }
    if (tid < 64) {
        const float4* wrow = (const float4*)(w_vec1 + tid * 64);
        float s = 0.f;
        #pragma unroll
        for (int c4 = 0; c4 < 16; ++c4) {
            float4 v = wrow[c4];
            s += v.x * w_edge[c4*4+0] + v.y * w_edge[c4*4+1]
               + v.z * w_edge[c4*4+2] + v.w * w_edge[c4*4+3];
        }
        weff[tid] = s;
    }
    __syncthreads();
    if (tid < 16) {
        const float4* srow = (const float4*)(w_sca + tid * W_SCA_COLS);
        const float4* vrow = (const float4*)(w_vec2 + tid * 64);
        float a2 = 0.f, b2 = 0.f;
        #pragma unroll
        for (int k4 = 0; k4 < 16; ++k4) {
            float4 sv = srow[k4];
            float4 vv = vrow[k4];
            float4 wv = *(const float4*)&weff[k4 * 4];
            a2 += fabsf(wv.x)*sv.x + fabsf(wv.y)*sv.y + fabsf(wv.z)*sv.z + fabsf(wv.w)*sv.w;
            b2 += wv.x*vv.x + wv.y*vv.y + wv.z*vv.z + wv.w*vv.w;
        }
        As[tid] = a2;
        Bs[tid] = b2;
    }
    __syncthreads();

    const int wv = tid >> 6, l = tid & 63;
    float* sw = sOut[wv];
    const int wbase = blockIdx.x * EPB + wv * 64;
    const float NL2E = -1.44269504088896340736f;
    const float C2   = -312.5f * 1.44269504088896340736f;

    for (int rep = 0; rep < REPS; ++rep) {
        if (REPS > 1) asm volatile("" ::: "memory");   // force real reloads per rep

        // --- per-edge loads ---
        const int na = __builtin_nontemporal_load(idxA + ec);
        const int nb = __builtin_nontemporal_load(idxB + ec);
        float f14[4];
        #pragma unroll
        for (int t = 0; t < 4; ++t)
            f14[t] = __builtin_nontemporal_load(feat + ec * 5 + 1 + t);

        F3 pa3, pb3;
        if (MODE == 3) {   // NOGATHER: computed pos; keep idx loads live
            asm volatile("" :: "v"(na), "v"(nb));
            const float t0 = (float)(e & 4095) * (1.0f / 409.6f);   // 0..10
            pa3.x = t0;        pa3.y = 0.5f * t0;  pa3.z = 0.25f * t0;
            pb3.x = 0.123f;    pb3.y = 0.456f;     pb3.z = 0.789f;
        } else {
            __builtin_memcpy(&pa3, pos + na * 3, 12);
            __builtin_memcpy(&pb3, pos + nb * 3, 12);
        }

        // --- geometry ---
        const float vx = pa3.x - pb3.x, vy = pa3.y - pb3.y, vz = pa3.z - pb3.z;
        const float d  = sqrtf(vx*vx + vy*vy + vz*vz);
        const float un = d * __builtin_amdgcn_rcpf(d + 1e-7f);
        const float u2 = un * un;
        const int ti = (int)(f14[0] + 2.f*f14[1] + 3.f*f14[2] + 4.f*f14[3] + 0.5f);

        float acc[16];
        if (MODE == 4) {   // SKEL: trivial acc from loaded data (loads live)
            const float s0 = d + f14[0] + f14[1] + f14[2] + f14[3];
            #pragma unroll
            for (int o = 0; o < 16; ++o) acc[o] = s0 + (float)o;
        } else {
            int glo = (int)ceilf((d - RAD) * 25.f);
            glo = glo < 0 ? 0 : (glo > NUM_GAUSS - NW ? NUM_GAUSS - NW : glo);
            const float x0 = d - (float)glo * 0.04f;
            {
                const float4* ar  = (const float4*)As;
                const float4* t0r = (const float4*)&wt5[ti * GP];
                #pragma unroll
                for (int qq = 0; qq < 4; ++qq) {
                    const float4 av = ar[qq];
                    const float4 tv = t0r[qq];
                    acc[4*qq+0] = fmaf(un, av.x, tv.x);
                    acc[4*qq+1] = fmaf(un, av.y, tv.y);
                    acc[4*qq+2] = fmaf(un, av.z, tv.z);
                    acc[4*qq+3] = fmaf(un, av.w, tv.w);
                }
            }
            const float* base = &wg[glo * GP];
            #pragma unroll
            for (int i = 0; i < NW; ++i) {
                const float t = x0 - (float)i * 0.04f;
                const float w = exp2f(C2 * t * t);
                const float4* row = (const float4*)(base + i * GP);
                #pragma unroll
                for (int qq = 0; qq < 4; ++qq) {
                    const float4 v = row[qq];
                    acc[4*qq+0] = fmaf(w, v.x, acc[4*qq+0]);
                    acc[4*qq+1] = fmaf(w, v.y, acc[4*qq+1]);
                    acc[4*qq+2] = fmaf(w, v.z, acc[4*qq+2]);
                    acc[4*qq+3] = fmaf(w, v.w, acc[4*qq+3]);
                }
            }
        }

        // --- transpose-store out_sca ---
        #pragma unroll
        for (int qq = 0; qq < 4; ++qq)
            *(float4*)&sw[l * GP + 4*qq] =
                make_float4(acc[4*qq], acc[4*qq+1], acc[4*qq+2], acc[4*qq+3]);
        __builtin_amdgcn_wave_barrier();
        #pragma unroll
        for (int s = 0; s < 4; ++s) {
            const int r = s * 16 + (l >> 2);
            const int cc = (l & 3) * 4;
            const f4 v = *(const f4*)&sw[r * GP + cc];
            if (MODE == 2) {
                asm volatile("" :: "v"(v.x), "v"(v.y), "v"(v.z), "v"(v.w));
            } else if (wbase + r < E) {
                __builtin_nontemporal_store(v, (f4*)(out + (size_t)(wbase + r) * 16 + cc));
            }
        }
        __builtin_amdgcn_wave_barrier();

        // --- gate ---
        #pragma unroll
        for (int oq = 0; oq < 16; oq += 4) {
            float ov[4];
            #pragma unroll
            for (int oi = 0; oi < 4; ++oi) {
                const int o = oq + oi;
                if (MODE == 4) {
                    ov[oi] = acc[o] * u2;
                } else {
                    float x = b_gate[o];
                    #pragma unroll
                    for (int p = 0; p < 16; ++p) x = fmaf(acc[p], w_gate[o * 16 + p], x);
                    const float gate = __builtin_amdgcn_rcpf(1.0f + exp2f(NL2E * x));
                    const float gv = gate * Bs[o];
                    ov[oi] = gv * gv * u2;
                }
            }
            *(float4*)&sw[l * GP + oq] = make_float4(ov[0], ov[1], ov[2], ov[3]);
        }
        __builtin_amdgcn_wave_barrier();
        float* outv = out + (size_t)E * 16;
        #pragma unroll
        for (int s = 0; s < 4; ++s) {
            const int r = s * 16 + (l >> 2);
            const int cc = (l & 3) * 4;
            const f4 v = *(const f4*)&sw[r * GP + cc];
            if (MODE == 2) {
                asm volatile("" :: "v"(v.x), "v"(v.y), "v"(v.z), "v"(v.w));
            } else if (wbase + r < E) {
                __builtin_nontemporal_store(v, (f4*)(outv + (size_t)(wbase + r) * 16 + cc));
            }
        }
        __builtin_amdgcn_wave_barrier();
    }
}

extern "C" void kernel_launch(void* const* d_in, const int* in_sizes, int n_in,
                              void* d_out, int out_size, void* d_ws, size_t ws_size,
                              hipStream_t stream) {
    const int*   idx    = (const int*)d_in[0];
    const float* feat   = (const float*)d_in[1];
    const float* pos    = (const float*)d_in[2];
    const float* w_edge = (const float*)d_in[3];
    const float* w_vec1 = (const float*)d_in[4];
    const float* w_vec2 = (const float*)d_in[5];
    const float* w_sca  = (const float*)d_in[6];
    const float* w_gate = (const float*)d_in[7];
    const float* b_gate = (const float*)d_in[8];
    float* out = (float*)d_out;

    const int E = in_sizes[0] / 2;
    const int nblk = (E + EPB - 1) / EPB;

    // Ablation dispatches (x3 inflated so each outranks the ~40us harness fills
    // in the top-5 rocprof rows). Junk outputs are overwritten by the final FULL.
    edge_kernel<1, 3><<<nblk, TPB, 0, stream>>>(idx, idx + E, feat, pos, w_edge,
                                                w_vec1, w_vec2, w_sca, w_gate, b_gate, out, E);
    edge_kernel<2, 3><<<nblk, TPB, 0, stream>>>(idx, idx + E, feat, pos, w_edge,
                                                w_vec1, w_vec2, w_sca, w_gate, b_gate, out, E);
    edge_kernel<3, 3><<<nblk, TPB, 0, stream>>>(idx, idx + E, feat, pos, w_edge,
                                                w_vec1, w_vec2, w_sca, w_gate, b_gate, out, E);
    edge_kernel<4, 3><<<nblk, TPB, 0, stream>>>(idx, idx + E, feat, pos, w_edge,
                                                w_vec1, w_vec2, w_sca, w_gate, b_gate, out, E);
    // Exact r11 semantics, correct output, LAST:
    edge_kernel<0, 1><<<nblk, TPB, 0, stream>>>(idx, idx + E, feat, pos, w_edge,
                                                w_vec1, w_vec2, w_sca, w_gate, b_gate, out, E);
}

// Round 14
// 28.792 us; speedup vs baseline: 4.3668x; 4.3668x over previous
//
#include <hip/hip_runtime.h>
#include <math.h>

#define NUM_HEADS 16
#define DIM_HID 64
#define NUM_GAUSS 251
#define W_SCA_COLS 320   // DIM_HID + 256
#define GP 20            // padded stride (floats): 80B, 16B-aligned
#define RAD 0.14f        // window radius
#define NW 8             // fixed window iterations
#define TPB 256
#define EPB 256
#define REPS 2           // MEASUREMENT ROUND: body runs twice (identical work,
                         // identical output). dur(r14)-dur(r11) = true warm
                         // marginal body cost M; 22.0 - M = fixed per-launch cost.

typedef float f4 __attribute__((ext_vector_type(4)));
struct F3 { float x, y, z; };

// ---------------------------------------------------------------------------
// r14 = exact r11 skeleton (22.0us best) + outer REPS=2 loop.
// Purpose: disambiguate fixed-vs-marginal cost using ONLY the timed graph
// clock (rocprof durs proven inflated: r7 42.2 rocprof vs 32.7 timed).
// asm memory clobber between reps forces full reload/recompute (no CSE).
// Output written twice with identical values -> deterministic, validates.
// ---------------------------------------------------------------------------
__global__ __launch_bounds__(TPB, 4) void edge_kernel(
    const int* __restrict__ idxA,     // [E]
    const int* __restrict__ idxB,     // [E]
    const float* __restrict__ feat,   // [E,5]
    const float* __restrict__ pos,    // [N,3]
    const float* __restrict__ w_edge, // [64]
    const float* __restrict__ w_vec1, // [64,64]
    const float* __restrict__ w_vec2, // [16,64]
    const float* __restrict__ w_sca,  // [16,320]
    const float* __restrict__ w_gate, // [16,16]
    const float* __restrict__ b_gate, // [16]
    float* __restrict__ out,
    int E)
{
    __shared__ __align__(16) float wg[NUM_GAUSS * GP];
    __shared__ __align__(16) float wt5[5 * GP];
    __shared__ __align__(16) float weff[64];
    __shared__ __align__(16) float As[16], Bs[16];
    __shared__ __align__(16) float sOut[4][64 * GP];

    const int tid = threadIdx.x;
    const int e  = blockIdx.x * EPB + tid;
    const int ec = (e < E) ? e : (E - 1);

    // --- block prologue (once) ---
    for (int j = tid; j < 16 * NUM_GAUSS; j += TPB) {
        int o = j / NUM_GAUSS;
        int g = j - o * NUM_GAUSS;
        wg[g * GP + o] = w_sca[o * W_SCA_COLS + DIM_HID + g];
    }
    if (tid < 80) {
        int t = tid >> 4, o = tid & 15;
        wt5[t * GP + o] = w_sca[o * W_SCA_COLS + DIM_HID + NUM_GAUSS + t];
    }
    if (tid < 64) {
        const float4* wrow = (const float4*)(w_vec1 + tid * 64);
        float s = 0.f;
        #pragma unroll
        for (int c4 = 0; c4 < 16; ++c4) {
            float4 v = wrow[c4];
            s += v.x * w_edge[c4*4+0] + v.y * w_edge[c4*4+1]
               + v.z * w_edge[c4*4+2] + v.w * w_edge[c4*4+3];
        }
        weff[tid] = s;
    }
    __syncthreads();
    if (tid < 16) {
        const float4* srow = (const float4*)(w_sca + tid * W_SCA_COLS);
        const float4* vrow = (const float4*)(w_vec2 + tid * 64);
        float a2 = 0.f, b2 = 0.f;
        #pragma unroll
        for (int k4 = 0; k4 < 16; ++k4) {
            float4 sv = srow[k4];
            float4 vv = vrow[k4];
            float4 wv = *(const float4*)&weff[k4 * 4];
            a2 += fabsf(wv.x)*sv.x + fabsf(wv.y)*sv.y + fabsf(wv.z)*sv.z + fabsf(wv.w)*sv.w;
            b2 += wv.x*vv.x + wv.y*vv.y + wv.z*vv.z + wv.w*vv.w;
        }
        As[tid] = a2;
        Bs[tid] = b2;
    }
    __syncthreads();

    const int wv = tid >> 6, l = tid & 63;
    float* sw = sOut[wv];
    const int wbase = blockIdx.x * EPB + wv * 64;
    const float NL2E = -1.44269504088896340736f;
    const float C2   = -312.5f * 1.44269504088896340736f;

    for (int rep = 0; rep < REPS; ++rep) {
        asm volatile("" ::: "memory");   // force full reload/recompute per rep

        // --- per-edge loads ---
        const int na = __builtin_nontemporal_load(idxA + ec);
        const int nb = __builtin_nontemporal_load(idxB + ec);
        float f14[4];
        #pragma unroll
        for (int t = 0; t < 4; ++t)
            f14[t] = __builtin_nontemporal_load(feat + ec * 5 + 1 + t);
        F3 pa3, pb3;
        __builtin_memcpy(&pa3, pos + na * 3, 12);
        __builtin_memcpy(&pb3, pos + nb * 3, 12);

        // --- geometry ---
        const float vx = pa3.x - pb3.x, vy = pa3.y - pb3.y, vz = pa3.z - pb3.z;
        const float d  = sqrtf(vx*vx + vy*vy + vz*vz);
        const float un = d * __builtin_amdgcn_rcpf(d + 1e-7f);
        const float u2 = un * un;
        const int ti = (int)(f14[0] + 2.f*f14[1] + 3.f*f14[2] + 4.f*f14[3] + 0.5f);

        int glo = (int)ceilf((d - RAD) * 25.f);
        glo = glo < 0 ? 0 : (glo > NUM_GAUSS - NW ? NUM_GAUSS - NW : glo);
        const float x0 = d - (float)glo * 0.04f;

        // --- acc init: un*A + etype row ---
        float acc[16];
        {
            const float4* ar  = (const float4*)As;
            const float4* t0r = (const float4*)&wt5[ti * GP];
            #pragma unroll
            for (int qq = 0; qq < 4; ++qq) {
                const float4 av = ar[qq];
                const float4 tv = t0r[qq];
                acc[4*qq+0] = fmaf(un, av.x, tv.x);
                acc[4*qq+1] = fmaf(un, av.y, tv.y);
                acc[4*qq+2] = fmaf(un, av.z, tv.z);
                acc[4*qq+3] = fmaf(un, av.w, tv.w);
            }
        }

        // --- fixed-8 gauss window ---
        {
            const float* base = &wg[glo * GP];
            #pragma unroll
            for (int i = 0; i < NW; ++i) {
                const float t = x0 - (float)i * 0.04f;
                const float w = exp2f(C2 * t * t);
                const float4* row = (const float4*)(base + i * GP);
                #pragma unroll
                for (int qq = 0; qq < 4; ++qq) {
                    const float4 v = row[qq];
                    acc[4*qq+0] = fmaf(w, v.x, acc[4*qq+0]);
                    acc[4*qq+1] = fmaf(w, v.y, acc[4*qq+1]);
                    acc[4*qq+2] = fmaf(w, v.z, acc[4*qq+2]);
                    acc[4*qq+3] = fmaf(w, v.w, acc[4*qq+3]);
                }
            }
        }

        // --- transpose-store out_sca ---
        #pragma unroll
        for (int qq = 0; qq < 4; ++qq)
            *(float4*)&sw[l * GP + 4*qq] =
                make_float4(acc[4*qq], acc[4*qq+1], acc[4*qq+2], acc[4*qq+3]);
        __builtin_amdgcn_wave_barrier();
        #pragma unroll
        for (int s = 0; s < 4; ++s) {
            const int r = s * 16 + (l >> 2);
            const int cc = (l & 3) * 4;
            const f4 v = *(const f4*)&sw[r * GP + cc];
            if (wbase + r < E)
                __builtin_nontemporal_store(v, (f4*)(out + (size_t)(wbase + r) * 16 + cc));
        }
        __builtin_amdgcn_wave_barrier();

        // --- gate ---
        #pragma unroll
        for (int oq = 0; oq < 16; oq += 4) {
            float ov[4];
            #pragma unroll
            for (int oi = 0; oi < 4; ++oi) {
                const int o = oq + oi;
                float x = b_gate[o];
                #pragma unroll
                for (int p = 0; p < 16; ++p) x = fmaf(acc[p], w_gate[o * 16 + p], x);
                const float gate = __builtin_amdgcn_rcpf(1.0f + exp2f(NL2E * x));
                const float gv = gate * Bs[o];
                ov[oi] = gv * gv * u2;
            }
            *(float4*)&sw[l * GP + oq] = make_float4(ov[0], ov[1], ov[2], ov[3]);
        }
        __builtin_amdgcn_wave_barrier();
        float* outv = out + (size_t)E * 16;
        #pragma unroll
        for (int s = 0; s < 4; ++s) {
            const int r = s * 16 + (l >> 2);
            const int cc = (l & 3) * 4;
            const f4 v = *(const f4*)&sw[r * GP + cc];
            if (wbase + r < E)
                __builtin_nontemporal_store(v, (f4*)(outv + (size_t)(wbase + r) * 16 + cc));
        }
        __builtin_amdgcn_wave_barrier();
    }
}

extern "C" void kernel_launch(void* const* d_in, const int* in_sizes, int n_in,
                              void* d_out, int out_size, void* d_ws, size_t ws_size,
                              hipStream_t stream) {
    const int*   idx    = (const int*)d_in[0];
    const float* feat   = (const float*)d_in[1];
    const float* pos    = (const float*)d_in[2];
    const float* w_edge = (const float*)d_in[3];
    const float* w_vec1 = (const float*)d_in[4];
    const float* w_vec2 = (const float*)d_in[5];
    const float* w_sca  = (const float*)d_in[6];
    const float* w_gate = (const float*)d_in[7];
    const float* b_gate = (const float*)d_in[8];
    float* out = (float*)d_out;

    const int E = in_sizes[0] / 2;
    const int nblk = (E + EPB - 1) / EPB;
    edge_kernel<<<nblk, TPB, 0, stream>>>(idx, idx + E, feat, pos,
                                          w_edge, w_vec1, w_vec2,
                                          w_sca, w_gate, b_gate, out, E);
}

// Round 15
// 21.327 us; speedup vs baseline: 5.8952x; 1.3500x over previous
//
#include <hip/hip_runtime.h>
#include <math.h>

#define NUM_HEADS 16
#define DIM_HID 64
#define NUM_GAUSS 251
#define W_SCA_COLS 320   // DIM_HID + 256
#define GP 20            // padded stride (floats): 80B, 16B-aligned
#define RAD 0.14f        // window radius
#define NW 8             // fixed window iterations
#define TPB 256
#define EPB 256

typedef float f4 __attribute__((ext_vector_type(4)));
struct F3 { float x, y, z; };

// ---------------------------------------------------------------------------
// r15 = r11 skeleton, ONE variable changed: input loads back to CACHEABLE.
// Evidence (r14 REPS=2 experiment): warm marginal body = 6.8us, "fixed" =
// 15us. Rep1 vs rep2 differ only in cache warmth -> the fixed cost is the
// per-replay COLD re-fetch of idx/feat, self-inflicted by r11's NT loads
// (no-allocate: 5.6MB of inputs never stay in L2 across graph replays).
// NT STORES stay (real win: 25.6MB write stream no longer evicts inputs).
//
// Algebraic collapse validated r2-r14 (absmax pinned 3.9e-3 vs 1.57e-2):
//   weff = w_vec1 @ w_edge;  A = |weff| @ w_sca[:,:64]^T;  B = w_vec2 @ weff
//   out_sca = un*A + etype_row + gauss_window(d)
//   output_vec = (sigmoid(out_sca@Wg^T + b) * B)^2 * un^2
// ---------------------------------------------------------------------------
__global__ __launch_bounds__(TPB, 4) void edge_kernel(
    const int* __restrict__ idxA,     // [E]
    const int* __restrict__ idxB,     // [E]
    const float* __restrict__ feat,   // [E,5]
    const float* __restrict__ pos,    // [N,3]
    const float* __restrict__ w_edge, // [64]
    const float* __restrict__ w_vec1, // [64,64]
    const float* __restrict__ w_vec2, // [16,64]
    const float* __restrict__ w_sca,  // [16,320]
    const float* __restrict__ w_gate, // [16,16]
    const float* __restrict__ b_gate, // [16]
    float* __restrict__ out,
    int E)
{
    __shared__ __align__(16) float wg[NUM_GAUSS * GP];
    __shared__ __align__(16) float wt5[5 * GP];
    __shared__ __align__(16) float weff[64];
    __shared__ __align__(16) float As[16], Bs[16];
    __shared__ __align__(16) float sOut[4][64 * GP];

    const int tid = threadIdx.x;
    const int e  = blockIdx.x * EPB + tid;
    const int ec = (e < E) ? e : (E - 1);

    // --- early per-edge loads: CACHEABLE (stay L2-resident across replays) ---
    const int na = idxA[ec];
    const int nb = idxB[ec];
    float f14[4];
    __builtin_memcpy(f14, feat + ec * 5 + 1, 16);  // one dwordx4
    F3 pa3, pb3;
    __builtin_memcpy(&pa3, pos + na * 3, 12);      // dwordx3
    __builtin_memcpy(&pb3, pos + nb * 3, 12);

    // --- block prologue ---
    for (int j = tid; j < 16 * NUM_GAUSS; j += TPB) {
        int o = j / NUM_GAUSS;
        int g = j - o * NUM_GAUSS;
        wg[g * GP + o] = w_sca[o * W_SCA_COLS + DIM_HID + g];
    }
    if (tid < 80) {
        int t = tid >> 4, o = tid & 15;
        wt5[t * GP + o] = w_sca[o * W_SCA_COLS + DIM_HID + NUM_GAUSS + t];
    }
    if (tid < 64) {
        const float4* wrow = (const float4*)(w_vec1 + tid * 64);
        float s = 0.f;
        #pragma unroll
        for (int c4 = 0; c4 < 16; ++c4) {
            float4 v = wrow[c4];
            s += v.x * w_edge[c4*4+0] + v.y * w_edge[c4*4+1]
               + v.z * w_edge[c4*4+2] + v.w * w_edge[c4*4+3];
        }
        weff[tid] = s;
    }
    __syncthreads();
    if (tid < 16) {
        const float4* srow = (const float4*)(w_sca + tid * W_SCA_COLS);
        const float4* vrow = (const float4*)(w_vec2 + tid * 64);
        float a2 = 0.f, b2 = 0.f;
        #pragma unroll
        for (int k4 = 0; k4 < 16; ++k4) {
            float4 sv = srow[k4];
            float4 vv = vrow[k4];
            float4 wv = *(const float4*)&weff[k4 * 4];
            a2 += fabsf(wv.x)*sv.x + fabsf(wv.y)*sv.y + fabsf(wv.z)*sv.z + fabsf(wv.w)*sv.w;
            b2 += wv.x*vv.x + wv.y*vv.y + wv.z*vv.z + wv.w*vv.w;
        }
        As[tid] = a2;
        Bs[tid] = b2;
    }
    __syncthreads();

    // --- geometry ---
    const float vx = pa3.x - pb3.x, vy = pa3.y - pb3.y, vz = pa3.z - pb3.z;
    const float d  = sqrtf(vx*vx + vy*vy + vz*vz);
    const float un = d * __builtin_amdgcn_rcpf(d + 1e-7f);
    const float u2 = un * un;
    const int ti = (int)(f14[0] + 2.f*f14[1] + 3.f*f14[2] + 4.f*f14[3] + 0.5f);

    int glo = (int)ceilf((d - RAD) * 25.f);
    glo = glo < 0 ? 0 : (glo > NUM_GAUSS - NW ? NUM_GAUSS - NW : glo);
    const float x0 = d - (float)glo * 0.04f;

    // --- acc init: un*A + etype row ---
    float acc[16];
    {
        const float4* ar  = (const float4*)As;
        const float4* t0r = (const float4*)&wt5[ti * GP];
        #pragma unroll
        for (int qq = 0; qq < 4; ++qq) {
            const float4 av = ar[qq];
            const float4 tv = t0r[qq];
            acc[4*qq+0] = fmaf(un, av.x, tv.x);
            acc[4*qq+1] = fmaf(un, av.y, tv.y);
            acc[4*qq+2] = fmaf(un, av.z, tv.z);
            acc[4*qq+3] = fmaf(un, av.w, tv.w);
        }
    }

    // --- fixed-8 gauss window ---
    {
        const float C2 = -312.5f * 1.44269504088896340736f;  // coeff * log2(e)
        const float* base = &wg[glo * GP];
        #pragma unroll
        for (int i = 0; i < NW; ++i) {
            const float t = x0 - (float)i * 0.04f;
            const float w = exp2f(C2 * t * t);
            const float4* row = (const float4*)(base + i * GP);
            #pragma unroll
            for (int qq = 0; qq < 4; ++qq) {
                const float4 v = row[qq];
                acc[4*qq+0] = fmaf(w, v.x, acc[4*qq+0]);
                acc[4*qq+1] = fmaf(w, v.y, acc[4*qq+1]);
                acc[4*qq+2] = fmaf(w, v.z, acc[4*qq+2]);
                acc[4*qq+3] = fmaf(w, v.w, acc[4*qq+3]);
            }
        }
    }

    // --- transpose-store out_sca: LDS tile -> contiguous NT stores ---
    const int wv = tid >> 6, l = tid & 63;
    float* sw = sOut[wv];
    const int wbase = blockIdx.x * EPB + wv * 64;
    #pragma unroll
    for (int qq = 0; qq < 4; ++qq)
        *(float4*)&sw[l * GP + 4*qq] =
            make_float4(acc[4*qq], acc[4*qq+1], acc[4*qq+2], acc[4*qq+3]);
    __builtin_amdgcn_wave_barrier();
    #pragma unroll
    for (int s = 0; s < 4; ++s) {
        const int r = s * 16 + (l >> 2);
        const int cc = (l & 3) * 4;
        const f4 v = *(const f4*)&sw[r * GP + cc];
        if (wbase + r < E)
            __builtin_nontemporal_store(v, (f4*)(out + (size_t)(wbase + r) * 16 + cc));
    }
    __builtin_amdgcn_wave_barrier();

    // --- gate: wave-uniform s_load weights ---
    const float NL2E = -1.44269504088896340736f;
    #pragma unroll
    for (int oq = 0; oq < 16; oq += 4) {
        float ov[4];
        #pragma unroll
        for (int oi = 0; oi < 4; ++oi) {
            const int o = oq + oi;
            float x = b_gate[o];
            #pragma unroll
            for (int p = 0; p < 16; ++p) x = fmaf(acc[p], w_gate[o * 16 + p], x);
            const float gate = __builtin_amdgcn_rcpf(1.0f + exp2f(NL2E * x));
            const float gv = gate * Bs[o];
            ov[oi] = gv * gv * u2;
        }
        *(float4*)&sw[l * GP + oq] = make_float4(ov[0], ov[1], ov[2], ov[3]);
    }
    __builtin_amdgcn_wave_barrier();
    float* outv = out + (size_t)E * 16;
    #pragma unroll
    for (int s = 0; s < 4; ++s) {
        const int r = s * 16 + (l >> 2);
        const int cc = (l & 3) * 4;
        const f4 v = *(const f4*)&sw[r * GP + cc];
        if (wbase + r < E)
            __builtin_nontemporal_store(v, (f4*)(outv + (size_t)(wbase + r) * 16 + cc));
    }
}

extern "C" void kernel_launch(void* const* d_in, const int* in_sizes, int n_in,
                              void* d_out, int out_size, void* d_ws, size_t ws_size,
                              hipStream_t stream) {
    const int*   idx    = (const int*)d_in[0];
    const float* feat   = (const float*)d_in[1];
    const float* pos    = (const float*)d_in[2];
    const float* w_edge = (const float*)d_in[3];
    const float* w_vec1 = (const float*)d_in[4];
    const float* w_vec2 = (const float*)d_in[5];
    const float* w_sca  = (const float*)d_in[6];
    const float* w_gate = (const float*)d_in[7];
    const float* b_gate = (const float*)d_in[8];
    float* out = (float*)d_out;

    const int E = in_sizes[0] / 2;
    const int nblk = (E + EPB - 1) / EPB;
    edge_kernel<<<nblk, TPB, 0, stream>>>(idx, idx + E, feat, pos,
                                          w_edge, w_vec1, w_vec2,
                                          w_sca, w_gate, b_gate, out, E);
}

// Round 16
// 20.197 us; speedup vs baseline: 6.2251x; 1.0560x over previous
//
#include <hip/hip_runtime.h>
#include <math.h>

#define NUM_HEADS 16
#define DIM_HID 64
#define NUM_GAUSS 251
#define W_SCA_COLS 320   // DIM_HID + 256
#define GP 20            // padded stride (floats): 80B, 16B-aligned
#define RAD 0.14f        // window radius
#define NW 8             // fixed window iterations
#define TPB 256
#define EPB 256
#define NSLICE 98        // per-XCD pos slices (782 blocks / 8 XCDs)
#define SLF4 383         // float4 per slice (ceil(37500/98))

typedef float f4 __attribute__((ext_vector_type(4)));
struct F3 { float x, y, z; };

// ---------------------------------------------------------------------------
// r16 = r15 skeleton + per-XCD pos L2-WARMING sweep.
// Cost structure measured (r14/r15): marginal warm body 6.8us, fixed 14.5us
// recurring per replay. Fixed cost survived block-count, occupancy, prologue,
// NT-load changes -> it is per-replay cold-cache re-establishment, dominated
// by 400K divergent pos gathers (each XCD pulls ~all 600KB of pos through a
// cold private L2, miss-queue-bound). Fix: during the latency-idle prologue,
// each block sequentially sweeps slice (blockIdx>>3)%98 of pos (f4 reads,
// sunk via asm) -> per-XCD full coverage at streaming BW; the random gather
// moves AFTER the prologue barrier onto a warm L2.
//
// Algebraic collapse validated r2-r15 (absmax pinned 3.9e-3 vs 1.57e-2):
//   weff = w_vec1 @ w_edge;  A = |weff| @ w_sca[:,:64]^T;  B = w_vec2 @ weff
//   out_sca = un*A + etype_row + gauss_window(d)
//   output_vec = (sigmoid(out_sca@Wg^T + b) * B)^2 * un^2
// ---------------------------------------------------------------------------
__global__ __launch_bounds__(TPB, 4) void edge_kernel(
    const int* __restrict__ idxA,     // [E]
    const int* __restrict__ idxB,     // [E]
    const float* __restrict__ feat,   // [E,5]
    const float* __restrict__ pos,    // [N,3]
    const float* __restrict__ w_edge, // [64]
    const float* __restrict__ w_vec1, // [64,64]
    const float* __restrict__ w_vec2, // [16,64]
    const float* __restrict__ w_sca,  // [16,320]
    const float* __restrict__ w_gate, // [16,16]
    const float* __restrict__ b_gate, // [16]
    float* __restrict__ out,
    int E, int nposf)                 // nposf = floats in pos (N*3)
{
    __shared__ __align__(16) float wg[NUM_GAUSS * GP];
    __shared__ __align__(16) float wt5[5 * GP];
    __shared__ __align__(16) float weff[64];
    __shared__ __align__(16) float As[16], Bs[16];
    __shared__ __align__(16) float sOut[4][64 * GP];

    const int tid = threadIdx.x;
    const int e  = blockIdx.x * EPB + tid;
    const int ec = (e < E) ? e : (E - 1);

    // --- early per-edge loads (cacheable): idx + feat ---
    const int na = idxA[ec];
    const int nb = idxB[ec];
    float f14[4];
    __builtin_memcpy(f14, feat + ec * 5 + 1, 16);  // one dwordx4

    // --- pos L2-warming sweep: sequential f4 reads of this XCD's slice ---
    {
        const f4* pos4 = (const f4*)pos;
        const int nf4 = nposf >> 2;                       // 37500
        const int s = (int)((blockIdx.x >> 3) % NSLICE);  // per-XCD slice id
        #pragma unroll
        for (int r = 0; r < 2; ++r) {
            const int k = r * TPB + tid;
            const int j = s * SLF4 + k;
            if (k < SLF4 && j < nf4) {
                const f4 v = pos4[j];
                asm volatile("" :: "v"(v.x), "v"(v.y), "v"(v.z), "v"(v.w));
            }
        }
    }

    // --- block prologue (staging overlaps the warming sweep's flight) ---
    for (int j = tid; j < 16 * NUM_GAUSS; j += TPB) {
        int o = j / NUM_GAUSS;
        int g = j - o * NUM_GAUSS;
        wg[g * GP + o] = w_sca[o * W_SCA_COLS + DIM_HID + g];
    }
    if (tid < 80) {
        int t = tid >> 4, o = tid & 15;
        wt5[t * GP + o] = w_sca[o * W_SCA_COLS + DIM_HID + NUM_GAUSS + t];
    }
    if (tid < 64) {
        const float4* wrow = (const float4*)(w_vec1 + tid * 64);
        float s = 0.f;
        #pragma unroll
        for (int c4 = 0; c4 < 16; ++c4) {
            float4 v = wrow[c4];
            s += v.x * w_edge[c4*4+0] + v.y * w_edge[c4*4+1]
               + v.z * w_edge[c4*4+2] + v.w * w_edge[c4*4+3];
        }
        weff[tid] = s;
    }
    __syncthreads();
    if (tid < 16) {
        const float4* srow = (const float4*)(w_sca + tid * W_SCA_COLS);
        const float4* vrow = (const float4*)(w_vec2 + tid * 64);
        float a2 = 0.f, b2 = 0.f;
        #pragma unroll
        for (int k4 = 0; k4 < 16; ++k4) {
            float4 sv = srow[k4];
            float4 vv = vrow[k4];
            float4 wv = *(const float4*)&weff[k4 * 4];
            a2 += fabsf(wv.x)*sv.x + fabsf(wv.y)*sv.y + fabsf(wv.z)*sv.z + fabsf(wv.w)*sv.w;
            b2 += wv.x*vv.x + wv.y*vv.y + wv.z*vv.z + wv.w*vv.w;
        }
        As[tid] = a2;
        Bs[tid] = b2;
    }
    __syncthreads();

    // --- pos gather NOW (L2 warm / lines in flight) ---
    F3 pa3, pb3;
    __builtin_memcpy(&pa3, pos + na * 3, 12);
    __builtin_memcpy(&pb3, pos + nb * 3, 12);

    // --- geometry ---
    const float vx = pa3.x - pb3.x, vy = pa3.y - pb3.y, vz = pa3.z - pb3.z;
    const float d  = sqrtf(vx*vx + vy*vy + vz*vz);
    const float un = d * __builtin_amdgcn_rcpf(d + 1e-7f);
    const float u2 = un * un;
    const int ti = (int)(f14[0] + 2.f*f14[1] + 3.f*f14[2] + 4.f*f14[3] + 0.5f);

    int glo = (int)ceilf((d - RAD) * 25.f);
    glo = glo < 0 ? 0 : (glo > NUM_GAUSS - NW ? NUM_GAUSS - NW : glo);
    const float x0 = d - (float)glo * 0.04f;

    // --- acc init: un*A + etype row ---
    float acc[16];
    {
        const float4* ar  = (const float4*)As;
        const float4* t0r = (const float4*)&wt5[ti * GP];
        #pragma unroll
        for (int qq = 0; qq < 4; ++qq) {
            const float4 av = ar[qq];
            const float4 tv = t0r[qq];
            acc[4*qq+0] = fmaf(un, av.x, tv.x);
            acc[4*qq+1] = fmaf(un, av.y, tv.y);
            acc[4*qq+2] = fmaf(un, av.z, tv.z);
            acc[4*qq+3] = fmaf(un, av.w, tv.w);
        }
    }

    // --- fixed-8 gauss window ---
    {
        const float C2 = -312.5f * 1.44269504088896340736f;  // coeff * log2(e)
        const float* base = &wg[glo * GP];
        #pragma unroll
        for (int i = 0; i < NW; ++i) {
            const float t = x0 - (float)i * 0.04f;
            const float w = exp2f(C2 * t * t);
            const float4* row = (const float4*)(base + i * GP);
            #pragma unroll
            for (int qq = 0; qq < 4; ++qq) {
                const float4 v = row[qq];
                acc[4*qq+0] = fmaf(w, v.x, acc[4*qq+0]);
                acc[4*qq+1] = fmaf(w, v.y, acc[4*qq+1]);
                acc[4*qq+2] = fmaf(w, v.z, acc[4*qq+2]);
                acc[4*qq+3] = fmaf(w, v.w, acc[4*qq+3]);
            }
        }
    }

    // --- transpose-store out_sca: LDS tile -> contiguous NT stores ---
    const int wv = tid >> 6, l = tid & 63;
    float* sw = sOut[wv];
    const int wbase = blockIdx.x * EPB + wv * 64;
    #pragma unroll
    for (int qq = 0; qq < 4; ++qq)
        *(float4*)&sw[l * GP + 4*qq] =
            make_float4(acc[4*qq], acc[4*qq+1], acc[4*qq+2], acc[4*qq+3]);
    __builtin_amdgcn_wave_barrier();
    #pragma unroll
    for (int s = 0; s < 4; ++s) {
        const int r = s * 16 + (l >> 2);
        const int cc = (l & 3) * 4;
        const f4 v = *(const f4*)&sw[r * GP + cc];
        if (wbase + r < E)
            __builtin_nontemporal_store(v, (f4*)(out + (size_t)(wbase + r) * 16 + cc));
    }
    __builtin_amdgcn_wave_barrier();

    // --- gate: wave-uniform s_load weights ---
    const float NL2E = -1.44269504088896340736f;
    #pragma unroll
    for (int oq = 0; oq < 16; oq += 4) {
        float ov[4];
        #pragma unroll
        for (int oi = 0; oi < 4; ++oi) {
            const int o = oq + oi;
            float x = b_gate[o];
            #pragma unroll
            for (int p = 0; p < 16; ++p) x = fmaf(acc[p], w_gate[o * 16 + p], x);
            const float gate = __builtin_amdgcn_rcpf(1.0f + exp2f(NL2E * x));
            const float gv = gate * Bs[o];
            ov[oi] = gv * gv * u2;
        }
        *(float4*)&sw[l * GP + oq] = make_float4(ov[0], ov[1], ov[2], ov[3]);
    }
    __builtin_amdgcn_wave_barrier();
    float* outv = out + (size_t)E * 16;
    #pragma unroll
    for (int s = 0; s < 4; ++s) {
        const int r = s * 16 + (l >> 2);
        const int cc = (l & 3) * 4;
        const f4 v = *(const f4*)&sw[r * GP + cc];
        if (wbase + r < E)
            __builtin_nontemporal_store(v, (f4*)(outv + (size_t)(wbase + r) * 16 + cc));
    }
}

extern "C" void kernel_launch(void* const* d_in, const int* in_sizes, int n_in,
                              void* d_out, int out_size, void* d_ws, size_t ws_size,
                              hipStream_t stream) {
    const int*   idx    = (const int*)d_in[0];
    const float* feat   = (const float*)d_in[1];
    const float* pos    = (const float*)d_in[2];
    const float* w_edge = (const float*)d_in[3];
    const float* w_vec1 = (const float*)d_in[4];
    const float* w_vec2 = (const float*)d_in[5];
    const float* w_sca  = (const float*)d_in[6];
    const float* w_gate = (const float*)d_in[7];
    const float* b_gate = (const float*)d_in[8];
    float* out = (float*)d_out;

    const int E = in_sizes[0] / 2;
    const int nposf = in_sizes[2];    // N*3 floats
    const int nblk = (E + EPB - 1) / EPB;
    edge_kernel<<<nblk, TPB, 0, stream>>>(idx, idx + E, feat, pos,
                                          w_edge, w_vec1, w_vec2,
                                          w_sca, w_gate, b_gate, out, E, nposf);
}

// Round 17
// 17.384 us; speedup vs baseline: 7.2324x; 1.1618x over previous
//
#include <hip/hip_runtime.h>
#include <math.h>

#define NUM_HEADS 16
#define DIM_HID 64
#define NUM_GAUSS 251
#define W_SCA_COLS 320   // DIM_HID + 256
#define GP 20            // padded stride (floats): 80B, 16B-aligned
#define RAD 0.14f        // window radius
#define NW 8             // fixed window iterations
#define TPB 512          // r17 single variable: 256 -> 512 (391 blocks, 1.53 gens/CU)
#define EPB 512
#define NSLICE 49        // per-XCD pos slices (391 blocks / 8 XCDs)
#define SLF4 766         // float4 per slice (ceil(37500/49))

typedef float f4 __attribute__((ext_vector_type(4)));
struct F3 { float x, y, z; };

// ---------------------------------------------------------------------------
// r17 = r16 skeleton, ONE variable: TPB 256->512 (block generations/CU
// 3.05 -> 1.53). Tests the last unfalsified structural theory: sequential
// block-generation cost (~2us/gen from r4/r8 slopes). All proven pieces kept:
// NT stores (+2.4), cacheable input loads (+0.7), per-XCD pos warming sweep
// (+1.1). Harness fills (268MB) sweep L2+L3 between replays -> every replay
// is cold by construction; warming converts random misses to streaming.
// launch_bounds(512,2): VGPR cap 128 (state ~60, no r6-style forced spill).
// LDS ~62KB -> 2 blocks/CU -> 16 waves/CU.
//
// Algebraic collapse validated r2-r16 (absmax pinned 3.9e-3 vs 1.57e-2):
//   weff = w_vec1 @ w_edge;  A = |weff| @ w_sca[:,:64]^T;  B = w_vec2 @ weff
//   out_sca = un*A + etype_row + gauss_window(d)
//   output_vec = (sigmoid(out_sca@Wg^T + b) * B)^2 * un^2
// ---------------------------------------------------------------------------
__global__ __launch_bounds__(TPB, 2) void edge_kernel(
    const int* __restrict__ idxA,     // [E]
    const int* __restrict__ idxB,     // [E]
    const float* __restrict__ feat,   // [E,5]
    const float* __restrict__ pos,    // [N,3]
    const float* __restrict__ w_edge, // [64]
    const float* __restrict__ w_vec1, // [64,64]
    const float* __restrict__ w_vec2, // [16,64]
    const float* __restrict__ w_sca,  // [16,320]
    const float* __restrict__ w_gate, // [16,16]
    const float* __restrict__ b_gate, // [16]
    float* __restrict__ out,
    int E, int nposf)                 // nposf = floats in pos (N*3)
{
    __shared__ __align__(16) float wg[NUM_GAUSS * GP];
    __shared__ __align__(16) float wt5[5 * GP];
    __shared__ __align__(16) float weff[64];
    __shared__ __align__(16) float As[16], Bs[16];
    __shared__ __align__(16) float sOut[8][64 * GP];   // 8 waves/block

    const int tid = threadIdx.x;
    const int e  = blockIdx.x * EPB + tid;
    const int ec = (e < E) ? e : (E - 1);

    // --- early per-edge loads (cacheable): idx + feat ---
    const int na = idxA[ec];
    const int nb = idxB[ec];
    float f14[4];
    __builtin_memcpy(f14, feat + ec * 5 + 1, 16);  // one dwordx4

    // --- pos L2-warming sweep: sequential f4 reads of this XCD's slice ---
    {
        const f4* pos4 = (const f4*)pos;
        const int nf4 = nposf >> 2;                       // 37500
        const int s = (int)((blockIdx.x >> 3) % NSLICE);  // per-XCD slice id
        #pragma unroll
        for (int r = 0; r < 2; ++r) {
            const int k = r * TPB + tid;
            const int j = s * SLF4 + k;
            if (k < SLF4 && j < nf4) {
                const f4 v = pos4[j];
                asm volatile("" :: "v"(v.x), "v"(v.y), "v"(v.z), "v"(v.w));
            }
        }
    }

    // --- block prologue (staging overlaps the warming sweep's flight) ---
    for (int j = tid; j < 16 * NUM_GAUSS; j += TPB) {
        int o = j / NUM_GAUSS;
        int g = j - o * NUM_GAUSS;
        wg[g * GP + o] = w_sca[o * W_SCA_COLS + DIM_HID + g];
    }
    if (tid < 80) {
        int t = tid >> 4, o = tid & 15;
        wt5[t * GP + o] = w_sca[o * W_SCA_COLS + DIM_HID + NUM_GAUSS + t];
    }
    if (tid < 64) {
        const float4* wrow = (const float4*)(w_vec1 + tid * 64);
        float s = 0.f;
        #pragma unroll
        for (int c4 = 0; c4 < 16; ++c4) {
            float4 v = wrow[c4];
            s += v.x * w_edge[c4*4+0] + v.y * w_edge[c4*4+1]
               + v.z * w_edge[c4*4+2] + v.w * w_edge[c4*4+3];
        }
        weff[tid] = s;
    }
    __syncthreads();
    if (tid < 16) {
        const float4* srow = (const float4*)(w_sca + tid * W_SCA_COLS);
        const float4* vrow = (const float4*)(w_vec2 + tid * 64);
        float a2 = 0.f, b2 = 0.f;
        #pragma unroll
        for (int k4 = 0; k4 < 16; ++k4) {
            float4 sv = srow[k4];
            float4 vv = vrow[k4];
            float4 wv = *(const float4*)&weff[k4 * 4];
            a2 += fabsf(wv.x)*sv.x + fabsf(wv.y)*sv.y + fabsf(wv.z)*sv.z + fabsf(wv.w)*sv.w;
            b2 += wv.x*vv.x + wv.y*vv.y + wv.z*vv.z + wv.w*vv.w;
        }
        As[tid] = a2;
        Bs[tid] = b2;
    }
    __syncthreads();

    // --- pos gather NOW (L2 warm / lines in flight) ---
    F3 pa3, pb3;
    __builtin_memcpy(&pa3, pos + na * 3, 12);
    __builtin_memcpy(&pb3, pos + nb * 3, 12);

    // --- geometry ---
    const float vx = pa3.x - pb3.x, vy = pa3.y - pb3.y, vz = pa3.z - pb3.z;
    const float d  = sqrtf(vx*vx + vy*vy + vz*vz);
    const float un = d * __builtin_amdgcn_rcpf(d + 1e-7f);
    const float u2 = un * un;
    const int ti = (int)(f14[0] + 2.f*f14[1] + 3.f*f14[2] + 4.f*f14[3] + 0.5f);

    int glo = (int)ceilf((d - RAD) * 25.f);
    glo = glo < 0 ? 0 : (glo > NUM_GAUSS - NW ? NUM_GAUSS - NW : glo);
    const float x0 = d - (float)glo * 0.04f;

    // --- acc init: un*A + etype row ---
    float acc[16];
    {
        const float4* ar  = (const float4*)As;
        const float4* t0r = (const float4*)&wt5[ti * GP];
        #pragma unroll
        for (int qq = 0; qq < 4; ++qq) {
            const float4 av = ar[qq];
            const float4 tv = t0r[qq];
            acc[4*qq+0] = fmaf(un, av.x, tv.x);
            acc[4*qq+1] = fmaf(un, av.y, tv.y);
            acc[4*qq+2] = fmaf(un, av.z, tv.z);
            acc[4*qq+3] = fmaf(un, av.w, tv.w);
        }
    }

    // --- fixed-8 gauss window ---
    {
        const float C2 = -312.5f * 1.44269504088896340736f;  // coeff * log2(e)
        const float* base = &wg[glo * GP];
        #pragma unroll
        for (int i = 0; i < NW; ++i) {
            const float t = x0 - (float)i * 0.04f;
            const float w = exp2f(C2 * t * t);
            const float4* row = (const float4*)(base + i * GP);
            #pragma unroll
            for (int qq = 0; qq < 4; ++qq) {
                const float4 v = row[qq];
                acc[4*qq+0] = fmaf(w, v.x, acc[4*qq+0]);
                acc[4*qq+1] = fmaf(w, v.y, acc[4*qq+1]);
                acc[4*qq+2] = fmaf(w, v.z, acc[4*qq+2]);
                acc[4*qq+3] = fmaf(w, v.w, acc[4*qq+3]);
            }
        }
    }

    // --- transpose-store out_sca: LDS tile -> contiguous NT stores ---
    const int wv = tid >> 6, l = tid & 63;
    float* sw = sOut[wv];
    const int wbase = blockIdx.x * EPB + wv * 64;
    #pragma unroll
    for (int qq = 0; qq < 4; ++qq)
        *(float4*)&sw[l * GP + 4*qq] =
            make_float4(acc[4*qq], acc[4*qq+1], acc[4*qq+2], acc[4*qq+3]);
    __builtin_amdgcn_wave_barrier();
    #pragma unroll
    for (int s = 0; s < 4; ++s) {
        const int r = s * 16 + (l >> 2);
        const int cc = (l & 3) * 4;
        const f4 v = *(const f4*)&sw[r * GP + cc];
        if (wbase + r < E)
            __builtin_nontemporal_store(v, (f4*)(out + (size_t)(wbase + r) * 16 + cc));
    }
    __builtin_amdgcn_wave_barrier();

    // --- gate: wave-uniform s_load weights ---
    const float NL2E = -1.44269504088896340736f;
    #pragma unroll
    for (int oq = 0; oq < 16; oq += 4) {
        float ov[4];
        #pragma unroll
        for (int oi = 0; oi < 4; ++oi) {
            const int o = oq + oi;
            float x = b_gate[o];
            #pragma unroll
            for (int p = 0; p < 16; ++p) x = fmaf(acc[p], w_gate[o * 16 + p], x);
            const float gate = __builtin_amdgcn_rcpf(1.0f + exp2f(NL2E * x));
            const float gv = gate * Bs[o];
            ov[oi] = gv * gv * u2;
        }
        *(float4*)&sw[l * GP + oq] = make_float4(ov[0], ov[1], ov[2], ov[3]);
    }
    __builtin_amdgcn_wave_barrier();
    float* outv = out + (size_t)E * 16;
    #pragma unroll
    for (int s = 0; s < 4; ++s) {
        const int r = s * 16 + (l >> 2);
        const int cc = (l & 3) * 4;
        const f4 v = *(const f4*)&sw[r * GP + cc];
        if (wbase + r < E)
            __builtin_nontemporal_store(v, (f4*)(outv + (size_t)(wbase + r) * 16 + cc));
    }
}

extern "C" void kernel_launch(void* const* d_in, const int* in_sizes, int n_in,
                              void* d_out, int out_size, void* d_ws, size_t ws_size,
                              hipStream_t stream) {
    const int*   idx    = (const int*)d_in[0];
    const float* feat   = (const float*)d_in[1];
    const float* pos    = (const float*)d_in[2];
    const float* w_edge = (const float*)d_in[3];
    const float* w_vec1 = (const float*)d_in[4];
    const float* w_vec2 = (const float*)d_in[5];
    const float* w_sca  = (const float*)d_in[6];
    const float* w_gate = (const float*)d_in[7];
    const float* b_gate = (const float*)d_in[8];
    float* out = (float*)d_out;

    const int E = in_sizes[0] / 2;
    const int nposf = in_sizes[2];    // N*3 floats
    const int nblk = (E + EPB - 1) / EPB;
    edge_kernel<<<nblk, TPB, 0, stream>>>(idx, idx + E, feat, pos,
                                          w_edge, w_vec1, w_vec2,
                                          w_sca, w_gate, b_gate, out, E, nposf);
}

// Round 18
// 16.643 us; speedup vs baseline: 7.5544x; 1.0445x over previous
//
#include <hip/hip_runtime.h>
#include <math.h>

#define NUM_HEADS 16
#define DIM_HID 64
#define NUM_GAUSS 251
#define W_SCA_COLS 320   // DIM_HID + 256
#define GP 20            // padded stride (floats): 80B, 16B-aligned
#define RAD 0.14f        // window radius
#define NW 8             // fixed window iterations
#define TPB 832          // 13 waves; 256 blocks = EXACTLY one block per CU
#define EPB 832
#define NWAVES 13
#define NSLICE 32        // per-XCD pos slices (256 blocks / 8 XCDs)
#define SLF4 1172        // float4 per slice (ceil(37500/32))

typedef float f4 __attribute__((ext_vector_type(4)));
struct F3 { float x, y, z; };

// ---------------------------------------------------------------------------
// r18 = r17 skeleton, generation lever pushed to its end: TPB 512->832,
// grid = 256 blocks = exactly 1 block/CU (generations 1.53 -> 1.0, no idle
// CUs). r16->r17 measured ~1.8us/generation; this removes the last 0.53.
// All proven pieces frozen: NT stores (+2.4), cacheable input loads (+0.7),
// per-XCD pos warming sweep (+1.1), post-barrier gather, LDS transpose
// stores, fixed-8 gauss window, wave-uniform s_load gate.
//
// Algebraic collapse validated r2-r17 (absmax pinned 3.9e-3 vs 1.57e-2):
//   weff = w_vec1 @ w_edge;  A = |weff| @ w_sca[:,:64]^T;  B = w_vec2 @ weff
//   out_sca = un*A + etype_row + gauss_window(d)
//   output_vec = (sigmoid(out_sca@Wg^T + b) * B)^2 * un^2
// ---------------------------------------------------------------------------
__global__ __launch_bounds__(TPB) void edge_kernel(
    const int* __restrict__ idxA,     // [E]
    const int* __restrict__ idxB,     // [E]
    const float* __restrict__ feat,   // [E,5]
    const float* __restrict__ pos,    // [N,3]
    const float* __restrict__ w_edge, // [64]
    const float* __restrict__ w_vec1, // [64,64]
    const float* __restrict__ w_vec2, // [16,64]
    const float* __restrict__ w_sca,  // [16,320]
    const float* __restrict__ w_gate, // [16,16]
    const float* __restrict__ b_gate, // [16]
    float* __restrict__ out,
    int E, int nposf)                 // nposf = floats in pos (N*3)
{
    __shared__ __align__(16) float wg[NUM_GAUSS * GP];
    __shared__ __align__(16) float wt5[5 * GP];
    __shared__ __align__(16) float weff[64];
    __shared__ __align__(16) float As[16], Bs[16];
    __shared__ __align__(16) float sOut[NWAVES][64 * GP];

    const int tid = threadIdx.x;
    const int e  = blockIdx.x * EPB + tid;
    const int ec = (e < E) ? e : (E - 1);

    // --- early per-edge loads (cacheable): idx + feat ---
    const int na = idxA[ec];
    const int nb = idxB[ec];
    float f14[4];
    __builtin_memcpy(f14, feat + ec * 5 + 1, 16);  // one dwordx4

    // --- pos L2-warming sweep: sequential f4 reads of this XCD's slice ---
    {
        const f4* pos4 = (const f4*)pos;
        const int nf4 = nposf >> 2;                       // 37500
        const int s = (int)((blockIdx.x >> 3) % NSLICE);  // per-XCD slice id
        #pragma unroll
        for (int r = 0; r < 2; ++r) {
            const int k = r * TPB + tid;
            const int j = s * SLF4 + k;
            if (k < SLF4 && j < nf4) {
                const f4 v = pos4[j];
                asm volatile("" :: "v"(v.x), "v"(v.y), "v"(v.z), "v"(v.w));
            }
        }
    }

    // --- block prologue (staging overlaps the warming sweep's flight) ---
    for (int j = tid; j < 16 * NUM_GAUSS; j += TPB) {
        int o = j / NUM_GAUSS;
        int g = j - o * NUM_GAUSS;
        wg[g * GP + o] = w_sca[o * W_SCA_COLS + DIM_HID + g];
    }
    if (tid < 80) {
        int t = tid >> 4, o = tid & 15;
        wt5[t * GP + o] = w_sca[o * W_SCA_COLS + DIM_HID + NUM_GAUSS + t];
    }
    if (tid < 64) {
        const float4* wrow = (const float4*)(w_vec1 + tid * 64);
        float s = 0.f;
        #pragma unroll
        for (int c4 = 0; c4 < 16; ++c4) {
            float4 v = wrow[c4];
            s += v.x * w_edge[c4*4+0] + v.y * w_edge[c4*4+1]
               + v.z * w_edge[c4*4+2] + v.w * w_edge[c4*4+3];
        }
        weff[tid] = s;
    }
    __syncthreads();
    if (tid < 16) {
        const float4* srow = (const float4*)(w_sca + tid * W_SCA_COLS);
        const float4* vrow = (const float4*)(w_vec2 + tid * 64);
        float a2 = 0.f, b2 = 0.f;
        #pragma unroll
        for (int k4 = 0; k4 < 16; ++k4) {
            float4 sv = srow[k4];
            float4 vv = vrow[k4];
            float4 wv = *(const float4*)&weff[k4 * 4];
            a2 += fabsf(wv.x)*sv.x + fabsf(wv.y)*sv.y + fabsf(wv.z)*sv.z + fabsf(wv.w)*sv.w;
            b2 += wv.x*vv.x + wv.y*vv.y + wv.z*vv.z + wv.w*vv.w;
        }
        As[tid] = a2;
        Bs[tid] = b2;
    }
    __syncthreads();

    // --- pos gather NOW (L2 warm / lines in flight) ---
    F3 pa3, pb3;
    __builtin_memcpy(&pa3, pos + na * 3, 12);
    __builtin_memcpy(&pb3, pos + nb * 3, 12);

    // --- geometry ---
    const float vx = pa3.x - pb3.x, vy = pa3.y - pb3.y, vz = pa3.z - pb3.z;
    const float d  = sqrtf(vx*vx + vy*vy + vz*vz);
    const float un = d * __builtin_amdgcn_rcpf(d + 1e-7f);
    const float u2 = un * un;
    const int ti = (int)(f14[0] + 2.f*f14[1] + 3.f*f14[2] + 4.f*f14[3] + 0.5f);

    int glo = (int)ceilf((d - RAD) * 25.f);
    glo = glo < 0 ? 0 : (glo > NUM_GAUSS - NW ? NUM_GAUSS - NW : glo);
    const float x0 = d - (float)glo * 0.04f;

    // --- acc init: un*A + etype row ---
    float acc[16];
    {
        const float4* ar  = (const float4*)As;
        const float4* t0r = (const float4*)&wt5[ti * GP];
        #pragma unroll
        for (int qq = 0; qq < 4; ++qq) {
            const float4 av = ar[qq];
            const float4 tv = t0r[qq];
            acc[4*qq+0] = fmaf(un, av.x, tv.x);
            acc[4*qq+1] = fmaf(un, av.y, tv.y);
            acc[4*qq+2] = fmaf(un, av.z, tv.z);
            acc[4*qq+3] = fmaf(un, av.w, tv.w);
        }
    }

    // --- fixed-8 gauss window ---
    {
        const float C2 = -312.5f * 1.44269504088896340736f;  // coeff * log2(e)
        const float* base = &wg[glo * GP];
        #pragma unroll
        for (int i = 0; i < NW; ++i) {
            const float t = x0 - (float)i * 0.04f;
            const float w = exp2f(C2 * t * t);
            const float4* row = (const float4*)(base + i * GP);
            #pragma unroll
            for (int qq = 0; qq < 4; ++qq) {
                const float4 v = row[qq];
                acc[4*qq+0] = fmaf(w, v.x, acc[4*qq+0]);
                acc[4*qq+1] = fmaf(w, v.y, acc[4*qq+1]);
                acc[4*qq+2] = fmaf(w, v.z, acc[4*qq+2]);
                acc[4*qq+3] = fmaf(w, v.w, acc[4*qq+3]);
            }
        }
    }

    // --- transpose-store out_sca: LDS tile -> contiguous NT stores ---
    const int wv = tid >> 6, l = tid & 63;
    float* sw = sOut[wv];
    const int wbase = blockIdx.x * EPB + wv * 64;
    #pragma unroll
    for (int qq = 0; qq < 4; ++qq)
        *(float4*)&sw[l * GP + 4*qq] =
            make_float4(acc[4*qq], acc[4*qq+1], acc[4*qq+2], acc[4*qq+3]);
    __builtin_amdgcn_wave_barrier();
    #pragma unroll
    for (int s = 0; s < 4; ++s) {
        const int r = s * 16 + (l >> 2);
        const int cc = (l & 3) * 4;
        const f4 v = *(const f4*)&sw[r * GP + cc];
        if (wbase + r < E)
            __builtin_nontemporal_store(v, (f4*)(out + (size_t)(wbase + r) * 16 + cc));
    }
    __builtin_amdgcn_wave_barrier();

    // --- gate: wave-uniform s_load weights ---
    const float NL2E = -1.44269504088896340736f;
    #pragma unroll
    for (int oq = 0; oq < 16; oq += 4) {
        float ov[4];
        #pragma unroll
        for (int oi = 0; oi < 4; ++oi) {
            const int o = oq + oi;
            float x = b_gate[o];
            #pragma unroll
            for (int p = 0; p < 16; ++p) x = fmaf(acc[p], w_gate[o * 16 + p], x);
            const float gate = __builtin_amdgcn_rcpf(1.0f + exp2f(NL2E * x));
            const float gv = gate * Bs[o];
            ov[oi] = gv * gv * u2;
        }
        *(float4*)&sw[l * GP + oq] = make_float4(ov[0], ov[1], ov[2], ov[3]);
    }
    __builtin_amdgcn_wave_barrier();
    float* outv = out + (size_t)E * 16;
    #pragma unroll
    for (int s = 0; s < 4; ++s) {
        const int r = s * 16 + (l >> 2);
        const int cc = (l & 3) * 4;
        const f4 v = *(const f4*)&sw[r * GP + cc];
        if (wbase + r < E)
            __builtin_nontemporal_store(v, (f4*)(outv + (size_t)(wbase + r) * 16 + cc));
    }
}

extern "C" void kernel_launch(void* const* d_in, const int* in_sizes, int n_in,
                              void* d_out, int out_size, void* d_ws, size_t ws_size,
                              hipStream_t stream) {
    const int*   idx    = (const int*)d_in[0];
    const float* feat   = (const float*)d_in[1];
    const float* pos    = (const float*)d_in[2];
    const float* w_edge = (const float*)d_in[3];
    const float* w_vec1 = (const float*)d_in[4];
    const float* w_vec2 = (const float*)d_in[5];
    const float* w_sca  = (const float*)d_in[6];
    const float* w_gate = (const float*)d_in[7];
    const float* b_gate = (const float*)d_in[8];
    float* out = (float*)d_out;

    const int E = in_sizes[0] / 2;
    const int nposf = in_sizes[2];    // N*3 floats
    const int nblk = (E + EPB - 1) / EPB;   // 241 for E=200000... see below
    // exactly-one-block-per-CU geometry: 256 x 832 covers E<=212992
    edge_kernel<<<nblk, TPB, 0, stream>>>(idx, idx + E, feat, pos,
                                          w_edge, w_vec1, w_vec2,
                                          w_sca, w_gate, b_gate, out, E, nposf);
}